// Round 3
// baseline (496.029 us; speedup 1.0000x reference)
//
#include <hip/hip_runtime.h>
#include <hip/hip_bf16.h>

#define B_ 2
#define S_ 2048
#define D_ 1024
#define H_ 16
#define HD_ 64

typedef short bf16x8 __attribute__((ext_vector_type(8)));
typedef short bf16x4 __attribute__((ext_vector_type(4)));
typedef float f32x4 __attribute__((ext_vector_type(4)));

__device__ __forceinline__ f32x4 mfma16(bf16x8 a, bf16x8 b, f32x4 c) {
    return __builtin_amdgcn_mfma_f32_16x16x32_bf16(a, b, c, 0, 0, 0);
}

__device__ __forceinline__ bf16x8 ldb8(const __hip_bfloat16* p) {
    return *reinterpret_cast<const bf16x8*>(p);
}

// ---------------- fp32 -> bf16 conversion ----------------
__global__ __launch_bounds__(256) void conv_kernel(const float* __restrict__ src,
                                                   __hip_bfloat16* __restrict__ dst, int n4) {
    int i = blockIdx.x * 256 + threadIdx.x;
    if (i >= n4) return;
    float4 f = reinterpret_cast<const float4*>(src)[i];
    union { __hip_bfloat16 h[4]; ushort4 u; } cv;
    cv.h[0] = __float2bfloat16(f.x);
    cv.h[1] = __float2bfloat16(f.y);
    cv.h[2] = __float2bfloat16(f.z);
    cv.h[3] = __float2bfloat16(f.w);
    reinterpret_cast<ushort4*>(dst)[i] = cv.u;
}

// ---------------- GEMM: Y = X @ W^T + bias ----------------
template <int MODE>
__global__ __launch_bounds__(256) void gemm_bt(
    const __hip_bfloat16* __restrict__ X, const __hip_bfloat16* __restrict__ Wt,
    const float* __restrict__ bias0, const float* __restrict__ bias1,
    const float* __restrict__ bias2,
    __hip_bfloat16* __restrict__ Yq, __hip_bfloat16* __restrict__ Yk,
    __hip_bfloat16* __restrict__ Yv, float* __restrict__ Yo,
    int M, int N, int K) {
    __shared__ __hip_bfloat16 As[128][40];
    __shared__ __hip_bfloat16 Bs[128][40];

    const int ntn = N >> 7;
    const int tm = blockIdx.x / ntn;
    const int tn = blockIdx.x % ntn;
    const int t = threadIdx.x;
    const int w = t >> 6, l = t & 63, g = l >> 4, c = l & 15;
    const int wr = w >> 1, wc = w & 1;

    const int arow = t >> 1;
    const int acol0 = (t & 1) * 16;

    const size_t xrow = (size_t)(tm * 128 + arow) * K;
    const size_t wrow = (size_t)(tn * 128 + arow) * K;

    f32x4 acc[4][4] = {};

    for (int k0 = 0; k0 < K; k0 += 32) {
        __syncthreads();
        *reinterpret_cast<bf16x8*>(&As[arow][acol0])     = ldb8(&X[xrow + k0 + acol0]);
        *reinterpret_cast<bf16x8*>(&As[arow][acol0 + 8]) = ldb8(&X[xrow + k0 + acol0 + 8]);
        *reinterpret_cast<bf16x8*>(&Bs[arow][acol0])     = ldb8(&Wt[wrow + k0 + acol0]);
        *reinterpret_cast<bf16x8*>(&Bs[arow][acol0 + 8]) = ldb8(&Wt[wrow + k0 + acol0 + 8]);
        __syncthreads();

        bf16x8 am[4], bn[4];
#pragma unroll
        for (int mi = 0; mi < 4; ++mi) am[mi] = ldb8(&As[wr * 64 + mi * 16 + c][g * 8]);
#pragma unroll
        for (int ni = 0; ni < 4; ++ni) bn[ni] = ldb8(&Bs[wc * 64 + ni * 16 + c][g * 8]);
#pragma unroll
        for (int mi = 0; mi < 4; ++mi)
#pragma unroll
            for (int ni = 0; ni < 4; ++ni)
                acc[mi][ni] = mfma16(am[mi], bn[ni], acc[mi][ni]);
    }

#pragma unroll
    for (int mi = 0; mi < 4; ++mi) {
        const int mbase = tm * 128 + wr * 64 + mi * 16 + g * 4;
#pragma unroll
        for (int ni = 0; ni < 4; ++ni) {
            const int n = tn * 128 + wc * 64 + ni * 16 + c;
#pragma unroll
            for (int r = 0; r < 4; ++r) {
                const int mm = mbase + r;
                float v = acc[mi][ni][r];
                if (MODE == 0) {
                    const float* bp = (n < 1024) ? bias0 : (n < 2048) ? bias1 : bias2;
                    const int nn = n & 1023;
                    v += bp[nn];
                    const int b = mm >> 11, s = mm & 2047;
                    const int h = nn >> 6, hd = nn & 63;
                    const size_t bh = (size_t)(b * H_ + h);
                    const __hip_bfloat16 bvv = __float2bfloat16(v);
                    if (n < 2048) {
                        __hip_bfloat16* dst = (n < 1024) ? Yq : Yk;
                        dst[(bh * S_ + s) * HD_ + hd] = bvv;
                    } else {
                        Yv[(bh * HD_ + hd) * S_ + s] = bvv;
                    }
                } else {
                    Yo[(size_t)mm * N + n] = v + bias0[n];
                }
            }
        }
    }
}

// ---------------- fused attention, swapped-QK^T layout ----------------
// grid: B*H*(S/16) blocks of 4 waves. Block owns 16 q-rows; wave w owns
// k in [w*512, (w+1)*512). mfma(K,Q) -> lane(g,c) holds 4 consecutive k
// (k = tile + g*4 + r) for q-row c: probs stored as float4 DIRECT from regs
// (lanes {c,c+16,c+32,c+48} fill one 64B line), P staged via 1 ds_write_b64
// into XOR-swizzled [16][64] rows for conflict-free ds_read_b128 A-frags.
__global__ __launch_bounds__(256) void attn_kernel(
    const __hip_bfloat16* __restrict__ Qh, const __hip_bfloat16* __restrict__ Kh,
    const __hip_bfloat16* __restrict__ Vt, const float* __restrict__ mask,
    float* __restrict__ probs, __hip_bfloat16* __restrict__ ctx) {
    union SMem {
        __hip_bfloat16 Pb[4][16 * 64];  // per-wave P stage, XOR-swizzled rows (8 KB)
        float Cred[4][16][68];          // ctx partial reduce (17408 B)
    };
    __shared__ SMem sm;
    __shared__ float sred[4][16];

    const int blk = blockIdx.x;
    const int qt = blk & 127;        // S/16
    const int bh = blk >> 7;
    const int b = bh >> 4, h = bh & 15;
    const int t = threadIdx.x;
    const int w = t >> 6, l = t & 63, g = l >> 4, c = l & 15;
    const int q0 = qt * 16;
    const int kbase = w * 512;
    const int swzc = (c & 7) << 3;   // element-granular XOR swizzle for row c

    const __hip_bfloat16* Qb = Qh + (size_t)bh * S_ * HD_;
    const __hip_bfloat16* Kb = Kh + (size_t)bh * S_ * HD_;
    const __hip_bfloat16* Vb = Vt + (size_t)bh * HD_ * S_;
    const float* mrow = mask + (size_t)b * S_;

    const bf16x8 aq0 = ldb8(&Qb[(q0 + c) * HD_ + g * 8]);
    const bf16x8 aq1 = ldb8(&Qb[(q0 + c) * HD_ + 32 + g * 8]);

    // ---- pass 1: partial denominator over this wave's k-range ----
    float lsum = 0.f;
    for (int ch = 0; ch < 8; ++ch) {
        const int k0 = kbase + ch * 64;
        bf16x8 kf[8];
#pragma unroll
        for (int sub = 0; sub < 4; ++sub) {
            kf[2 * sub]     = ldb8(&Kb[(k0 + sub * 16 + c) * HD_ + g * 8]);
            kf[2 * sub + 1] = ldb8(&Kb[(k0 + sub * 16 + c) * HD_ + 32 + g * 8]);
        }
#pragma unroll
        for (int sub = 0; sub < 4; ++sub) {
            f32x4 a = {};
            a = mfma16(kf[2 * sub], aq0, a);
            a = mfma16(kf[2 * sub + 1], aq1, a);
#pragma unroll
            for (int r = 0; r < 4; ++r)
                lsum += __expf(a[r] * 0.125f + mrow[k0 + sub * 16 + g * 4 + r]);
        }
    }
    lsum += __shfl_xor(lsum, 16);
    lsum += __shfl_xor(lsum, 32);
    if (g == 0) sred[w][c] = lsum;
    __syncthreads();
    const float inv = 1.0f / (sred[0][c] + sred[1][c] + sred[2][c] + sred[3][c]);

    // ---- pass 2: probs (direct from regs) + partial PV ----
    f32x4 cacc[4] = {};
    float* prow = probs + ((size_t)bh * S_ + q0 + c) * S_;
    for (int ch = 0; ch < 8; ++ch) {
        const int k0 = kbase + ch * 64;
        bf16x8 kf[8];
#pragma unroll
        for (int sub = 0; sub < 4; ++sub) {
            kf[2 * sub]     = ldb8(&Kb[(k0 + sub * 16 + c) * HD_ + g * 8]);
            kf[2 * sub + 1] = ldb8(&Kb[(k0 + sub * 16 + c) * HD_ + 32 + g * 8]);
        }
#pragma unroll
        for (int sub = 0; sub < 4; ++sub) {
            f32x4 a = {};
            a = mfma16(kf[2 * sub], aq0, a);
            a = mfma16(kf[2 * sub + 1], aq1, a);
            float4 o;
            float p[4];
#pragma unroll
            for (int r = 0; r < 4; ++r)
                p[r] = __expf(a[r] * 0.125f + mrow[k0 + sub * 16 + g * 4 + r]) * inv;
            o.x = p[0]; o.y = p[1]; o.z = p[2]; o.w = p[3];
            *reinterpret_cast<float4*>(&prow[k0 + sub * 16 + g * 4]) = o;
            union { __hip_bfloat16 hh[4]; bf16x4 v; } pk;
#pragma unroll
            for (int r = 0; r < 4; ++r) pk.hh[r] = __float2bfloat16(p[r]);
            *reinterpret_cast<bf16x4*>(
                &sm.Pb[w][c * 64 + ((sub * 16 + g * 4) ^ swzc)]) = pk.v;
        }
        asm volatile("s_waitcnt lgkmcnt(0)" ::: "memory");
        __builtin_amdgcn_sched_barrier(0);
#pragma unroll
        for (int half = 0; half < 2; ++half) {
            const bf16x8 ap = ldb8(&sm.Pb[w][c * 64 + ((half * 32 + g * 8) ^ swzc)]);
            const int kk = k0 + half * 32;
#pragma unroll
            for (int n = 0; n < 4; ++n) {
                const bf16x8 bv = ldb8(&Vb[(n * 16 + c) * S_ + kk + g * 8]);
                cacc[n] = mfma16(ap, bv, cacc[n]);
            }
        }
    }

    // ---- cross-wave PV reduce ----
    __syncthreads();
#pragma unroll
    for (int n = 0; n < 4; ++n)
#pragma unroll
        for (int r = 0; r < 4; ++r)
            sm.Cred[w][g * 4 + r][n * 16 + c] = cacc[n][r];
    __syncthreads();

    const int row = t >> 4, col4 = (t & 15) * 4;
    float4 s0 = *reinterpret_cast<const float4*>(&sm.Cred[0][row][col4]);
    float4 s1 = *reinterpret_cast<const float4*>(&sm.Cred[1][row][col4]);
    float4 s2 = *reinterpret_cast<const float4*>(&sm.Cred[2][row][col4]);
    float4 s3 = *reinterpret_cast<const float4*>(&sm.Cred[3][row][col4]);
    union { __hip_bfloat16 hh[4]; ushort4 u; } ov;
    ov.hh[0] = __float2bfloat16(s0.x + s1.x + s2.x + s3.x);
    ov.hh[1] = __float2bfloat16(s0.y + s1.y + s2.y + s3.y);
    ov.hh[2] = __float2bfloat16(s0.z + s1.z + s2.z + s3.z);
    ov.hh[3] = __float2bfloat16(s0.w + s1.w + s2.w + s3.w);
    *reinterpret_cast<ushort4*>(
        &ctx[((size_t)b * S_ + q0 + row) * D_ + h * HD_ + col4]) = ov.u;
}

// ---------------- launch ----------------
extern "C" void kernel_launch(void* const* d_in, const int* in_sizes, int n_in,
                              void* d_out, int out_size, void* d_ws, size_t ws_size,
                              hipStream_t stream) {
    const float* hs   = (const float*)d_in[0];
    const float* mask = (const float*)d_in[1];
    const float* Wq   = (const float*)d_in[2];
    const float* bq   = (const float*)d_in[3];
    const float* Wk   = (const float*)d_in[4];
    const float* bk   = (const float*)d_in[5];
    const float* Wv   = (const float*)d_in[6];
    const float* bv   = (const float*)d_in[7];
    const float* Wo   = (const float*)d_in[8];
    const float* bo   = (const float*)d_in[9];

    float* out   = (float*)d_out;
    float* probs = out + (size_t)B_ * S_ * D_;

    const size_t MD = (size_t)B_ * S_ * D_;  // 4096*1024
    __hip_bfloat16* hsb   = (__hip_bfloat16*)d_ws;
    __hip_bfloat16* wqkvb = hsb + MD;
    __hip_bfloat16* wob   = wqkvb + 3u * 1024u * 1024u;
    __hip_bfloat16* Qh    = wob + (size_t)1024 * 1024;
    __hip_bfloat16* Kh    = Qh + MD;
    __hip_bfloat16* Vt    = Kh + MD;
    __hip_bfloat16* ctxb  = Vt + MD;

    conv_kernel<<<4096, 256, 0, stream>>>(hs, hsb, (int)(MD / 4));
    conv_kernel<<<1024, 256, 0, stream>>>(Wq, wqkvb, 262144);
    conv_kernel<<<1024, 256, 0, stream>>>(Wk, wqkvb + 1048576, 262144);
    conv_kernel<<<1024, 256, 0, stream>>>(Wv, wqkvb + 2097152, 262144);
    conv_kernel<<<1024, 256, 0, stream>>>(Wo, wob, 262144);

    gemm_bt<0><<<32 * 24, 256, 0, stream>>>(hsb, wqkvb, bq, bk, bv,
                                            Qh, Kh, Vt, nullptr, 4096, 3072, 1024);

    attn_kernel<<<B_ * H_ * (S_ / 16), 256, 0, stream>>>(Qh, Kh, Vt, mask, probs, ctxb);

    gemm_bt<1><<<32 * 8, 256, 0, stream>>>(ctxb, wob, bo, nullptr, nullptr,
                                           nullptr, nullptr, nullptr, out, 4096, 1024, 1024);
}

// Round 5
// 395.758 us; speedup vs baseline: 1.2534x; 1.2534x over previous
//
#include <hip/hip_runtime.h>
#include <hip/hip_bf16.h>

#define B_ 2
#define S_ 2048
#define D_ 1024
#define H_ 16
#define HD_ 64

typedef short bf16x8 __attribute__((ext_vector_type(8)));
typedef short bf16x4 __attribute__((ext_vector_type(4)));
typedef float f32x4 __attribute__((ext_vector_type(4)));

__device__ __forceinline__ f32x4 mfma16(bf16x8 a, bf16x8 b, f32x4 c) {
    return __builtin_amdgcn_mfma_f32_16x16x32_bf16(a, b, c, 0, 0, 0);
}

__device__ __forceinline__ bf16x8 ldb8(const __hip_bfloat16* p) {
    return *reinterpret_cast<const bf16x8*>(p);
}

// ---------------- fp32 -> bf16 conversion ----------------
__global__ __launch_bounds__(256) void conv_kernel(const float* __restrict__ src,
                                                   __hip_bfloat16* __restrict__ dst, int n4) {
    int i = blockIdx.x * 256 + threadIdx.x;
    if (i >= n4) return;
    float4 f = reinterpret_cast<const float4*>(src)[i];
    union { __hip_bfloat16 h[4]; ushort4 u; } cv;
    cv.h[0] = __float2bfloat16(f.x);
    cv.h[1] = __float2bfloat16(f.y);
    cv.h[2] = __float2bfloat16(f.z);
    cv.h[3] = __float2bfloat16(f.w);
    reinterpret_cast<ushort4*>(dst)[i] = cv.u;
}

// ---------------- GEMM: Y = X @ W^T + bias ----------------
template <int MODE>
__global__ __launch_bounds__(256) void gemm_bt(
    const __hip_bfloat16* __restrict__ X, const __hip_bfloat16* __restrict__ Wt,
    const float* __restrict__ bias0, const float* __restrict__ bias1,
    const float* __restrict__ bias2,
    __hip_bfloat16* __restrict__ Yq, __hip_bfloat16* __restrict__ Yk,
    __hip_bfloat16* __restrict__ Yv, float* __restrict__ Yo,
    int M, int N, int K) {
    __shared__ __hip_bfloat16 As[128][40];
    __shared__ __hip_bfloat16 Bs[128][40];

    const int ntn = N >> 7;
    const int tm = blockIdx.x / ntn;
    const int tn = blockIdx.x % ntn;
    const int t = threadIdx.x;
    const int w = t >> 6, l = t & 63, g = l >> 4, c = l & 15;
    const int wr = w >> 1, wc = w & 1;

    const int arow = t >> 1;
    const int acol0 = (t & 1) * 16;

    const size_t xrow = (size_t)(tm * 128 + arow) * K;
    const size_t wrow = (size_t)(tn * 128 + arow) * K;

    f32x4 acc[4][4] = {};

    for (int k0 = 0; k0 < K; k0 += 32) {
        __syncthreads();
        *reinterpret_cast<bf16x8*>(&As[arow][acol0])     = ldb8(&X[xrow + k0 + acol0]);
        *reinterpret_cast<bf16x8*>(&As[arow][acol0 + 8]) = ldb8(&X[xrow + k0 + acol0 + 8]);
        *reinterpret_cast<bf16x8*>(&Bs[arow][acol0])     = ldb8(&Wt[wrow + k0 + acol0]);
        *reinterpret_cast<bf16x8*>(&Bs[arow][acol0 + 8]) = ldb8(&Wt[wrow + k0 + acol0 + 8]);
        __syncthreads();

        bf16x8 am[4], bn[4];
#pragma unroll
        for (int mi = 0; mi < 4; ++mi) am[mi] = ldb8(&As[wr * 64 + mi * 16 + c][g * 8]);
#pragma unroll
        for (int ni = 0; ni < 4; ++ni) bn[ni] = ldb8(&Bs[wc * 64 + ni * 16 + c][g * 8]);
#pragma unroll
        for (int mi = 0; mi < 4; ++mi)
#pragma unroll
            for (int ni = 0; ni < 4; ++ni)
                acc[mi][ni] = mfma16(am[mi], bn[ni], acc[mi][ni]);
    }

#pragma unroll
    for (int mi = 0; mi < 4; ++mi) {
        const int mbase = tm * 128 + wr * 64 + mi * 16 + g * 4;
#pragma unroll
        for (int ni = 0; ni < 4; ++ni) {
            const int n = tn * 128 + wc * 64 + ni * 16 + c;
#pragma unroll
            for (int r = 0; r < 4; ++r) {
                const int mm = mbase + r;
                float v = acc[mi][ni][r];
                if (MODE == 0) {
                    const float* bp = (n < 1024) ? bias0 : (n < 2048) ? bias1 : bias2;
                    const int nn = n & 1023;
                    v += bp[nn];
                    const int b = mm >> 11, s = mm & 2047;
                    const int h = nn >> 6, hd = nn & 63;
                    const size_t bh = (size_t)(b * H_ + h);
                    const __hip_bfloat16 bvv = __float2bfloat16(v);
                    if (n < 2048) {
                        __hip_bfloat16* dst = (n < 1024) ? Yq : Yk;
                        dst[(bh * S_ + s) * HD_ + hd] = bvv;
                    } else {
                        Yv[(bh * HD_ + hd) * S_ + s] = bvv;
                    }
                } else {
                    Yo[(size_t)mm * N + n] = v + bias0[n];
                }
            }
        }
    }
}

// ---------------- fused attention, single QK^T pass, P in registers ----------------
// grid: B*H*(S/16) blocks of 8 waves (512 thr). Block owns 16 q-rows; wave w
// owns k in [w*256, (w+1)*256). Swapped mfma(K,Q): lane (g,c) holds
// k = base+16s+4g+r for q-row c. P~ = exp(s+m) kept packed bf16 in 32 VGPRs
// (UNNORMALIZED; probs multiply by inv at store, ctx multiplies by inv in the
// final cross-wave reduce via invsh[row]).
__global__ __launch_bounds__(512) void attn_kernel(
    const __hip_bfloat16* __restrict__ Qh, const __hip_bfloat16* __restrict__ Kh,
    const __hip_bfloat16* __restrict__ Vt, const float* __restrict__ mask,
    float* __restrict__ probs, __hip_bfloat16* __restrict__ ctx) {
    __shared__ float Cred[8][16][68];   // 34816 B
    __shared__ float sred[8][16];
    __shared__ float invsh[16];

    const int blk = blockIdx.x;
    const int qt = blk & 127;        // S/16
    const int bh = blk >> 7;
    const int b = bh >> 4, h = bh & 15;
    const int t = threadIdx.x;
    const int w = t >> 6, l = t & 63, g = l >> 4, c = l & 15;
    const int q0 = qt * 16;
    const int kbase = w * 256;

    const __hip_bfloat16* Qb = Qh + (size_t)bh * S_ * HD_;
    const __hip_bfloat16* Kb = Kh + (size_t)bh * S_ * HD_;
    const __hip_bfloat16* Vb = Vt + (size_t)bh * HD_ * S_;
    const float* mrow = mask + (size_t)b * S_;

    const bf16x8 aq0 = ldb8(&Qb[(q0 + c) * HD_ + g * 8]);
    const bf16x8 aq1 = ldb8(&Qb[(q0 + c) * HD_ + 32 + g * 8]);

    // ---- pass 1: QK^T + exp once; P~ packed bf16 into u[16][2] ----
    unsigned int u[16][2];
    float lsum = 0.f;
#pragma unroll
    for (int s = 0; s < 16; ++s) {
        const int kk = kbase + s * 16;
        const bf16x8 k0 = ldb8(&Kb[(kk + c) * HD_ + g * 8]);
        const bf16x8 k1 = ldb8(&Kb[(kk + c) * HD_ + 32 + g * 8]);
        f32x4 a = {};
        a = mfma16(k0, aq0, a);
        a = mfma16(k1, aq1, a);
        const float4 mk = *reinterpret_cast<const float4*>(&mrow[kk + g * 4]);
        const float p0 = __expf(a[0] * 0.125f + mk.x);
        const float p1 = __expf(a[1] * 0.125f + mk.y);
        const float p2 = __expf(a[2] * 0.125f + mk.z);
        const float p3 = __expf(a[3] * 0.125f + mk.w);
        lsum += (p0 + p1) + (p2 + p3);
        union { __hip_bfloat16 hh[2]; unsigned int ui; } pk0, pk1;
        pk0.hh[0] = __float2bfloat16(p0); pk0.hh[1] = __float2bfloat16(p1);
        pk1.hh[0] = __float2bfloat16(p2); pk1.hh[1] = __float2bfloat16(p3);
        u[s][0] = pk0.ui;
        u[s][1] = pk1.ui;
    }
    lsum += __shfl_xor(lsum, 16);
    lsum += __shfl_xor(lsum, 32);
    if (g == 0) sred[w][c] = lsum;
    __syncthreads();
    float tot = 0.f;
#pragma unroll
    for (int w8 = 0; w8 < 8; ++w8) tot += sred[w8][c];
    const float inv = 1.0f / tot;
    if (w == 0 && g == 0) invsh[c] = inv;   // per-q-row inv for the ctx epilogue

    // ---- pass 2: probs from regs (NT stores) + PV via in-register shuffles ----
    f32x4 cacc[4] = {};
    float* prow = probs + ((size_t)bh * S_ + q0 + c) * S_ + kbase;
    const int src0 = 32 * (g & 1) + c;
    const int src1 = src0 + 16;
    const int sigma = g >> 1;
#pragma unroll
    for (int W = 0; W < 8; ++W) {
        // probs: subs 2W, 2W+1
#pragma unroll
        for (int ss = 0; ss < 2; ++ss) {
            const int s = 2 * W + ss;
            f32x4 o;
            o[0] = __uint_as_float(u[s][0] << 16) * inv;
            o[1] = __uint_as_float(u[s][0] & 0xffff0000u) * inv;
            o[2] = __uint_as_float(u[s][1] << 16) * inv;
            o[3] = __uint_as_float(u[s][1] & 0xffff0000u) * inv;
            __builtin_nontemporal_store(o, reinterpret_cast<f32x4*>(&prow[s * 16 + g * 4]));
        }
        // A-frag: af.ui[jj] = u[2W+sigma][jj&1] from lane 32(g&1)+16(jj>>1)+c
        const unsigned int x00 = __shfl(u[2 * W][0], src0);
        const unsigned int x10 = __shfl(u[2 * W + 1][0], src0);
        const unsigned int x01 = __shfl(u[2 * W][1], src0);
        const unsigned int x11 = __shfl(u[2 * W + 1][1], src0);
        const unsigned int x02 = __shfl(u[2 * W][0], src1);
        const unsigned int x12 = __shfl(u[2 * W + 1][0], src1);
        const unsigned int x03 = __shfl(u[2 * W][1], src1);
        const unsigned int x13 = __shfl(u[2 * W + 1][1], src1);
        union { unsigned int ui[4]; bf16x8 v; } af;
        af.ui[0] = sigma ? x10 : x00;
        af.ui[1] = sigma ? x11 : x01;
        af.ui[2] = sigma ? x12 : x02;
        af.ui[3] = sigma ? x13 : x03;
        const int kk = kbase + 32 * W;
#pragma unroll
        for (int n = 0; n < 4; ++n) {
            const bf16x8 bv = ldb8(&Vb[(n * 16 + c) * S_ + kk + g * 8]);
            cacc[n] = mfma16(af.v, bv, cacc[n]);
        }
    }

    // ---- cross-wave PV reduce (8-way), normalized by invsh[row] ----
#pragma unroll
    for (int n = 0; n < 4; ++n)
#pragma unroll
        for (int r = 0; r < 4; ++r)
            Cred[w][g * 4 + r][n * 16 + c] = cacc[n][r];
    __syncthreads();

    // 512 threads: each reduces 2 floats: row = t>>5, col2 = (t&31)*2
    const int row = t >> 5, col2 = (t & 31) * 2;
    float a0 = 0.f, a1 = 0.f;
#pragma unroll
    for (int w8 = 0; w8 < 8; ++w8) {
        const float2 vv = *reinterpret_cast<const float2*>(&Cred[w8][row][col2]);
        a0 += vv.x; a1 += vv.y;
    }
    const float fin = invsh[row];
    union { __hip_bfloat16 hh[2]; unsigned int ui; } ov;
    ov.hh[0] = __float2bfloat16(a0 * fin);
    ov.hh[1] = __float2bfloat16(a1 * fin);
    *reinterpret_cast<unsigned int*>(
        &ctx[((size_t)b * S_ + q0 + row) * D_ + h * HD_ + col2]) = ov.ui;
}

// ---------------- launch ----------------
extern "C" void kernel_launch(void* const* d_in, const int* in_sizes, int n_in,
                              void* d_out, int out_size, void* d_ws, size_t ws_size,
                              hipStream_t stream) {
    const float* hs   = (const float*)d_in[0];
    const float* mask = (const float*)d_in[1];
    const float* Wq   = (const float*)d_in[2];
    const float* bq   = (const float*)d_in[3];
    const float* Wk   = (const float*)d_in[4];
    const float* bk   = (const float*)d_in[5];
    const float* Wv   = (const float*)d_in[6];
    const float* bv   = (const float*)d_in[7];
    const float* Wo   = (const float*)d_in[8];
    const float* bo   = (const float*)d_in[9];

    float* out   = (float*)d_out;
    float* probs = out + (size_t)B_ * S_ * D_;

    const size_t MD = (size_t)B_ * S_ * D_;  // 4096*1024
    __hip_bfloat16* hsb   = (__hip_bfloat16*)d_ws;
    __hip_bfloat16* wqkvb = hsb + MD;
    __hip_bfloat16* wob   = wqkvb + 3u * 1024u * 1024u;
    __hip_bfloat16* Qh    = wob + (size_t)1024 * 1024;
    __hip_bfloat16* Kh    = Qh + MD;
    __hip_bfloat16* Vt    = Kh + MD;
    __hip_bfloat16* ctxb  = Vt + MD;

    conv_kernel<<<4096, 256, 0, stream>>>(hs, hsb, (int)(MD / 4));
    conv_kernel<<<1024, 256, 0, stream>>>(Wq, wqkvb, 262144);
    conv_kernel<<<1024, 256, 0, stream>>>(Wk, wqkvb + 1048576, 262144);
    conv_kernel<<<1024, 256, 0, stream>>>(Wv, wqkvb + 2097152, 262144);
    conv_kernel<<<1024, 256, 0, stream>>>(Wo, wob, 262144);

    gemm_bt<0><<<32 * 24, 256, 0, stream>>>(hsb, wqkvb, bq, bk, bv,
                                            Qh, Kh, Vt, nullptr, 4096, 3072, 1024);

    attn_kernel<<<B_ * H_ * (S_ / 16), 512, 0, stream>>>(Qh, Kh, Vt, mask, probs, ctxb);

    gemm_bt<1><<<32 * 8, 256, 0, stream>>>(ctxb, wob, bo, nullptr, nullptr,
                                           nullptr, nullptr, nullptr, out, 4096, 1024, 1024);
}

// Round 6
// 374.542 us; speedup vs baseline: 1.3244x; 1.0566x over previous
//
#include <hip/hip_runtime.h>
#include <hip/hip_bf16.h>

#define B_ 2
#define S_ 2048
#define D_ 1024
#define H_ 16
#define HD_ 64

typedef short bf16x8 __attribute__((ext_vector_type(8)));
typedef short bf16x4 __attribute__((ext_vector_type(4)));
typedef float f32x4 __attribute__((ext_vector_type(4)));

__device__ __forceinline__ f32x4 mfma16(bf16x8 a, bf16x8 b, f32x4 c) {
    return __builtin_amdgcn_mfma_f32_16x16x32_bf16(a, b, c, 0, 0, 0);
}

__device__ __forceinline__ bf16x8 ldb8(const __hip_bfloat16* p) {
    return *reinterpret_cast<const bf16x8*>(p);
}

// ---------------- fp32 -> bf16 conversion ----------------
__global__ __launch_bounds__(256) void conv_kernel(const float* __restrict__ src,
                                                   __hip_bfloat16* __restrict__ dst, int n4) {
    int i = blockIdx.x * 256 + threadIdx.x;
    if (i >= n4) return;
    float4 f = reinterpret_cast<const float4*>(src)[i];
    union { __hip_bfloat16 h[4]; ushort4 u; } cv;
    cv.h[0] = __float2bfloat16(f.x);
    cv.h[1] = __float2bfloat16(f.y);
    cv.h[2] = __float2bfloat16(f.z);
    cv.h[3] = __float2bfloat16(f.w);
    reinterpret_cast<ushort4*>(dst)[i] = cv.u;
}

// ---------------- GEMM: Y = X @ W^T + bias ----------------
template <int MODE>
__global__ __launch_bounds__(256) void gemm_bt(
    const __hip_bfloat16* __restrict__ X, const __hip_bfloat16* __restrict__ Wt,
    const float* __restrict__ bias0, const float* __restrict__ bias1,
    const float* __restrict__ bias2,
    __hip_bfloat16* __restrict__ Yq, __hip_bfloat16* __restrict__ Yk,
    __hip_bfloat16* __restrict__ Yv, float* __restrict__ Yo,
    int M, int N, int K) {
    __shared__ __hip_bfloat16 As[128][40];
    __shared__ __hip_bfloat16 Bs[128][40];

    const int ntn = N >> 7;
    const int tm = blockIdx.x / ntn;
    const int tn = blockIdx.x % ntn;
    const int t = threadIdx.x;
    const int w = t >> 6, l = t & 63, g = l >> 4, c = l & 15;
    const int wr = w >> 1, wc = w & 1;

    const int arow = t >> 1;
    const int acol0 = (t & 1) * 16;

    const size_t xrow = (size_t)(tm * 128 + arow) * K;
    const size_t wrow = (size_t)(tn * 128 + arow) * K;

    f32x4 acc[4][4] = {};

    for (int k0 = 0; k0 < K; k0 += 32) {
        __syncthreads();
        *reinterpret_cast<bf16x8*>(&As[arow][acol0])     = ldb8(&X[xrow + k0 + acol0]);
        *reinterpret_cast<bf16x8*>(&As[arow][acol0 + 8]) = ldb8(&X[xrow + k0 + acol0 + 8]);
        *reinterpret_cast<bf16x8*>(&Bs[arow][acol0])     = ldb8(&Wt[wrow + k0 + acol0]);
        *reinterpret_cast<bf16x8*>(&Bs[arow][acol0 + 8]) = ldb8(&Wt[wrow + k0 + acol0 + 8]);
        __syncthreads();

        bf16x8 am[4], bn[4];
#pragma unroll
        for (int mi = 0; mi < 4; ++mi) am[mi] = ldb8(&As[wr * 64 + mi * 16 + c][g * 8]);
#pragma unroll
        for (int ni = 0; ni < 4; ++ni) bn[ni] = ldb8(&Bs[wc * 64 + ni * 16 + c][g * 8]);
#pragma unroll
        for (int mi = 0; mi < 4; ++mi)
#pragma unroll
            for (int ni = 0; ni < 4; ++ni)
                acc[mi][ni] = mfma16(am[mi], bn[ni], acc[mi][ni]);
    }

#pragma unroll
    for (int mi = 0; mi < 4; ++mi) {
        const int mbase = tm * 128 + wr * 64 + mi * 16 + g * 4;
#pragma unroll
        for (int ni = 0; ni < 4; ++ni) {
            const int n = tn * 128 + wc * 64 + ni * 16 + c;
#pragma unroll
            for (int r = 0; r < 4; ++r) {
                const int mm = mbase + r;
                float v = acc[mi][ni][r];
                if (MODE == 0) {
                    const float* bp = (n < 1024) ? bias0 : (n < 2048) ? bias1 : bias2;
                    const int nn = n & 1023;
                    v += bp[nn];
                    const int b = mm >> 11, s = mm & 2047;
                    const int h = nn >> 6, hd = nn & 63;
                    const size_t bh = (size_t)(b * H_ + h);
                    const __hip_bfloat16 bvv = __float2bfloat16(v);
                    if (n < 2048) {
                        __hip_bfloat16* dst = (n < 1024) ? Yq : Yk;
                        dst[(bh * S_ + s) * HD_ + hd] = bvv;
                    } else {
                        Yv[(bh * HD_ + hd) * S_ + s] = bvv;
                    }
                } else {
                    Yo[(size_t)mm * N + n] = v + bias0[n];
                }
            }
        }
    }
}

// ---------------- fused attention: QBLK=32 via dual q-groups per wave ----------------
// grid: B*H*(S/32) blocks of 8 waves. Block owns 32 q-rows (two 16-row groups
// A,B); wave w owns k in [w*256, (w+1)*256). Swapped mfma(K,Q) per group with
// SHARED K/mask/V loads. P~ = exp(s+m) packed bf16, 32 VGPRs per group.
// Probs normalized at store (NT float4); ctx normalized in the epilogue.
__global__ __launch_bounds__(512, 4) void attn_kernel(
    const __hip_bfloat16* __restrict__ Qh, const __hip_bfloat16* __restrict__ Kh,
    const __hip_bfloat16* __restrict__ Vt, const float* __restrict__ mask,
    float* __restrict__ probs, __hip_bfloat16* __restrict__ ctx) {
    __shared__ float Cred[8][16][68];   // 34816 B, reused for group A then B
    __shared__ float sred[8][32];
    __shared__ float invsh[32];

    const int blk = blockIdx.x;
    const int qt = blk & 63;         // S/32
    const int bh = blk >> 6;
    const int b = bh >> 4, h = bh & 15;
    const int t = threadIdx.x;
    const int w = t >> 6, l = t & 63, g = l >> 4, c = l & 15;
    const int q0 = qt * 32;
    const int kbase = w * 256;

    const __hip_bfloat16* Qb = Qh + (size_t)bh * S_ * HD_;
    const __hip_bfloat16* Kb = Kh + (size_t)bh * S_ * HD_;
    const __hip_bfloat16* Vb = Vt + (size_t)bh * HD_ * S_;
    const float* mrow = mask + (size_t)b * S_;

    const bf16x8 aqA0 = ldb8(&Qb[(q0 + c) * HD_ + g * 8]);
    const bf16x8 aqA1 = ldb8(&Qb[(q0 + c) * HD_ + 32 + g * 8]);
    const bf16x8 aqB0 = ldb8(&Qb[(q0 + 16 + c) * HD_ + g * 8]);
    const bf16x8 aqB1 = ldb8(&Qb[(q0 + 16 + c) * HD_ + 32 + g * 8]);

    // ---- pass 1: QK^T + exp once; P~ packed bf16 (per group) ----
    unsigned int uA[16][2], uB[16][2];
    float lsumA = 0.f, lsumB = 0.f;
#pragma unroll
    for (int s = 0; s < 16; ++s) {
        const int kk = kbase + s * 16;
        const bf16x8 k0 = ldb8(&Kb[(kk + c) * HD_ + g * 8]);
        const bf16x8 k1 = ldb8(&Kb[(kk + c) * HD_ + 32 + g * 8]);
        f32x4 aA = {}, aB = {};
        aA = mfma16(k0, aqA0, aA);
        aA = mfma16(k1, aqA1, aA);
        aB = mfma16(k0, aqB0, aB);
        aB = mfma16(k1, aqB1, aB);
        const float4 mk = *reinterpret_cast<const float4*>(&mrow[kk + g * 4]);
        const float pA0 = __expf(aA[0] * 0.125f + mk.x);
        const float pA1 = __expf(aA[1] * 0.125f + mk.y);
        const float pA2 = __expf(aA[2] * 0.125f + mk.z);
        const float pA3 = __expf(aA[3] * 0.125f + mk.w);
        const float pB0 = __expf(aB[0] * 0.125f + mk.x);
        const float pB1 = __expf(aB[1] * 0.125f + mk.y);
        const float pB2 = __expf(aB[2] * 0.125f + mk.z);
        const float pB3 = __expf(aB[3] * 0.125f + mk.w);
        lsumA += (pA0 + pA1) + (pA2 + pA3);
        lsumB += (pB0 + pB1) + (pB2 + pB3);
        union { __hip_bfloat16 hh[2]; unsigned int ui; } w0, w1;
        w0.hh[0] = __float2bfloat16(pA0); w0.hh[1] = __float2bfloat16(pA1);
        w1.hh[0] = __float2bfloat16(pA2); w1.hh[1] = __float2bfloat16(pA3);
        uA[s][0] = w0.ui; uA[s][1] = w1.ui;
        w0.hh[0] = __float2bfloat16(pB0); w0.hh[1] = __float2bfloat16(pB1);
        w1.hh[0] = __float2bfloat16(pB2); w1.hh[1] = __float2bfloat16(pB3);
        uB[s][0] = w0.ui; uB[s][1] = w1.ui;
    }
    lsumA += __shfl_xor(lsumA, 16); lsumA += __shfl_xor(lsumA, 32);
    lsumB += __shfl_xor(lsumB, 16); lsumB += __shfl_xor(lsumB, 32);
    if (g == 0) { sred[w][c] = lsumA; sred[w][16 + c] = lsumB; }
    __syncthreads();
    float totA = 0.f, totB = 0.f;
#pragma unroll
    for (int w8 = 0; w8 < 8; ++w8) { totA += sred[w8][c]; totB += sred[w8][16 + c]; }
    const float invA = 1.0f / totA;
    const float invB = 1.0f / totB;
    if (w == 0 && g == 0) { invsh[c] = invA; invsh[16 + c] = invB; }

    // ---- pass 2: probs (NT, from regs) + PV, both groups interleaved ----
    f32x4 caccA[4] = {}, caccB[4] = {};
    float* prowA = probs + ((size_t)bh * S_ + q0 + c) * S_ + kbase;
    float* prowB = probs + ((size_t)bh * S_ + q0 + 16 + c) * S_ + kbase;
    const int src0 = 32 * (g & 1) + c;
    const int src1 = src0 + 16;
    const int sigma = g >> 1;
#pragma unroll
    for (int W = 0; W < 8; ++W) {
#pragma unroll
        for (int ss = 0; ss < 2; ++ss) {
            const int s = 2 * W + ss;
            f32x4 oA, oB;
            oA[0] = __uint_as_float(uA[s][0] << 16) * invA;
            oA[1] = __uint_as_float(uA[s][0] & 0xffff0000u) * invA;
            oA[2] = __uint_as_float(uA[s][1] << 16) * invA;
            oA[3] = __uint_as_float(uA[s][1] & 0xffff0000u) * invA;
            __builtin_nontemporal_store(oA, reinterpret_cast<f32x4*>(&prowA[s * 16 + g * 4]));
            oB[0] = __uint_as_float(uB[s][0] << 16) * invB;
            oB[1] = __uint_as_float(uB[s][0] & 0xffff0000u) * invB;
            oB[2] = __uint_as_float(uB[s][1] << 16) * invB;
            oB[3] = __uint_as_float(uB[s][1] & 0xffff0000u) * invB;
            __builtin_nontemporal_store(oB, reinterpret_cast<f32x4*>(&prowB[s * 16 + g * 4]));
        }
        // A-frags: af.ui[jj] = u[2W+sigma][jj&1] from lane 32(g&1)+16(jj>>1)+c
        union { unsigned int ui[4]; bf16x8 v; } afA, afB;
        {
            const unsigned int x00 = __shfl(uA[2 * W][0], src0);
            const unsigned int x10 = __shfl(uA[2 * W + 1][0], src0);
            const unsigned int x01 = __shfl(uA[2 * W][1], src0);
            const unsigned int x11 = __shfl(uA[2 * W + 1][1], src0);
            const unsigned int x02 = __shfl(uA[2 * W][0], src1);
            const unsigned int x12 = __shfl(uA[2 * W + 1][0], src1);
            const unsigned int x03 = __shfl(uA[2 * W][1], src1);
            const unsigned int x13 = __shfl(uA[2 * W + 1][1], src1);
            afA.ui[0] = sigma ? x10 : x00;
            afA.ui[1] = sigma ? x11 : x01;
            afA.ui[2] = sigma ? x12 : x02;
            afA.ui[3] = sigma ? x13 : x03;
        }
        {
            const unsigned int x00 = __shfl(uB[2 * W][0], src0);
            const unsigned int x10 = __shfl(uB[2 * W + 1][0], src0);
            const unsigned int x01 = __shfl(uB[2 * W][1], src0);
            const unsigned int x11 = __shfl(uB[2 * W + 1][1], src0);
            const unsigned int x02 = __shfl(uB[2 * W][0], src1);
            const unsigned int x12 = __shfl(uB[2 * W + 1][0], src1);
            const unsigned int x03 = __shfl(uB[2 * W][1], src1);
            const unsigned int x13 = __shfl(uB[2 * W + 1][1], src1);
            afB.ui[0] = sigma ? x10 : x00;
            afB.ui[1] = sigma ? x11 : x01;
            afB.ui[2] = sigma ? x12 : x02;
            afB.ui[3] = sigma ? x13 : x03;
        }
        const int kk = kbase + 32 * W;
#pragma unroll
        for (int n = 0; n < 4; ++n) {
            const bf16x8 bv = ldb8(&Vb[(n * 16 + c) * S_ + kk + g * 8]);  // shared
            caccA[n] = mfma16(afA.v, bv, caccA[n]);
            caccB[n] = mfma16(afB.v, bv, caccB[n]);
        }
    }

    // ---- cross-wave PV reduce: group A, then group B through same LDS ----
#pragma unroll
    for (int n = 0; n < 4; ++n)
#pragma unroll
        for (int r = 0; r < 4; ++r)
            Cred[w][g * 4 + r][n * 16 + c] = caccA[n][r];
    __syncthreads();
    {
        const int row = t >> 5, col2 = (t & 31) * 2;
        float a0 = 0.f, a1 = 0.f;
#pragma unroll
        for (int w8 = 0; w8 < 8; ++w8) {
            const float2 vv = *reinterpret_cast<const float2*>(&Cred[w8][row][col2]);
            a0 += vv.x; a1 += vv.y;
        }
        const float fin = invsh[row];
        union { __hip_bfloat16 hh[2]; unsigned int ui; } ov;
        ov.hh[0] = __float2bfloat16(a0 * fin);
        ov.hh[1] = __float2bfloat16(a1 * fin);
        *reinterpret_cast<unsigned int*>(
            &ctx[((size_t)b * S_ + q0 + row) * D_ + h * HD_ + col2]) = ov.ui;
    }
    __syncthreads();
#pragma unroll
    for (int n = 0; n < 4; ++n)
#pragma unroll
        for (int r = 0; r < 4; ++r)
            Cred[w][g * 4 + r][n * 16 + c] = caccB[n][r];
    __syncthreads();
    {
        const int row = t >> 5, col2 = (t & 31) * 2;
        float a0 = 0.f, a1 = 0.f;
#pragma unroll
        for (int w8 = 0; w8 < 8; ++w8) {
            const float2 vv = *reinterpret_cast<const float2*>(&Cred[w8][row][col2]);
            a0 += vv.x; a1 += vv.y;
        }
        const float fin = invsh[16 + row];
        union { __hip_bfloat16 hh[2]; unsigned int ui; } ov;
        ov.hh[0] = __float2bfloat16(a0 * fin);
        ov.hh[1] = __float2bfloat16(a1 * fin);
        *reinterpret_cast<unsigned int*>(
            &ctx[((size_t)b * S_ + q0 +16 + row) * D_ + h * HD_ + col2]) = ov.ui;
    }
}

// ---------------- launch ----------------
extern "C" void kernel_launch(void* const* d_in, const int* in_sizes, int n_in,
                              void* d_out, int out_size, void* d_ws, size_t ws_size,
                              hipStream_t stream) {
    const float* hs   = (const float*)d_in[0];
    const float* mask = (const float*)d_in[1];
    const float* Wq   = (const float*)d_in[2];
    const float* bq   = (const float*)d_in[3];
    const float* Wk   = (const float*)d_in[4];
    const float* bk   = (const float*)d_in[5];
    const float* Wv   = (const float*)d_in[6];
    const float* bv   = (const float*)d_in[7];
    const float* Wo   = (const float*)d_in[8];
    const float* bo   = (const float*)d_in[9];

    float* out   = (float*)d_out;
    float* probs = out + (size_t)B_ * S_ * D_;

    const size_t MD = (size_t)B_ * S_ * D_;  // 4096*1024
    __hip_bfloat16* hsb   = (__hip_bfloat16*)d_ws;
    __hip_bfloat16* wqkvb = hsb + MD;
    __hip_bfloat16* wob   = wqkvb + 3u * 1024u * 1024u;
    __hip_bfloat16* Qh    = wob + (size_t)1024 * 1024;
    __hip_bfloat16* Kh    = Qh + MD;
    __hip_bfloat16* Vt    = Kh + MD;
    __hip_bfloat16* ctxb  = Vt + MD;

    conv_kernel<<<4096, 256, 0, stream>>>(hs, hsb, (int)(MD / 4));
    conv_kernel<<<1024, 256, 0, stream>>>(Wq, wqkvb, 262144);
    conv_kernel<<<1024, 256, 0, stream>>>(Wk, wqkvb + 1048576, 262144);
    conv_kernel<<<1024, 256, 0, stream>>>(Wv, wqkvb + 2097152, 262144);
    conv_kernel<<<1024, 256, 0, stream>>>(Wo, wob, 262144);

    gemm_bt<0><<<32 * 24, 256, 0, stream>>>(hsb, wqkvb, bq, bk, bv,
                                            Qh, Kh, Vt, nullptr, 4096, 3072, 1024);

    attn_kernel<<<B_ * H_ * (S_ / 32), 512, 0, stream>>>(Qh, Kh, Vt, mask, probs, ctxb);

    gemm_bt<1><<<32 * 8, 256, 0, stream>>>(ctxb, wob, bo, nullptr, nullptr,
                                           nullptr, nullptr, nullptr, out, 4096, 1024, 1024);
}

// Round 7
// 372.601 us; speedup vs baseline: 1.3313x; 1.0052x over previous
//
#include <hip/hip_runtime.h>
#include <hip/hip_bf16.h>

#define B_ 2
#define S_ 2048
#define D_ 1024
#define H_ 16
#define HD_ 64

typedef short bf16x8 __attribute__((ext_vector_type(8)));
typedef short bf16x4 __attribute__((ext_vector_type(4)));
typedef float f32x4 __attribute__((ext_vector_type(4)));

__device__ __forceinline__ f32x4 mfma16(bf16x8 a, bf16x8 b, f32x4 c) {
    return __builtin_amdgcn_mfma_f32_16x16x32_bf16(a, b, c, 0, 0, 0);
}

__device__ __forceinline__ bf16x8 ldb8(const __hip_bfloat16* p) {
    return *reinterpret_cast<const bf16x8*>(p);
}

// ---------------- fp32 -> bf16 conversion ----------------
__global__ __launch_bounds__(256) void conv_kernel(const float* __restrict__ src,
                                                   __hip_bfloat16* __restrict__ dst, int n4) {
    int i = blockIdx.x * 256 + threadIdx.x;
    if (i >= n4) return;
    float4 f = reinterpret_cast<const float4*>(src)[i];
    union { __hip_bfloat16 h[4]; ushort4 u; } cv;
    cv.h[0] = __float2bfloat16(f.x);
    cv.h[1] = __float2bfloat16(f.y);
    cv.h[2] = __float2bfloat16(f.z);
    cv.h[3] = __float2bfloat16(f.w);
    reinterpret_cast<ushort4*>(dst)[i] = cv.u;
}

// ---------------- GEMM: Y = X @ W^T + bias ----------------
template <int MODE>
__global__ __launch_bounds__(256) void gemm_bt(
    const __hip_bfloat16* __restrict__ X, const __hip_bfloat16* __restrict__ Wt,
    const float* __restrict__ bias0, const float* __restrict__ bias1,
    const float* __restrict__ bias2,
    __hip_bfloat16* __restrict__ Yq, __hip_bfloat16* __restrict__ Yk,
    __hip_bfloat16* __restrict__ Yv, float* __restrict__ Yo,
    int M, int N, int K) {
    __shared__ __hip_bfloat16 As[128][40];
    __shared__ __hip_bfloat16 Bs[128][40];

    const int ntn = N >> 7;
    const int tm = blockIdx.x / ntn;
    const int tn = blockIdx.x % ntn;
    const int t = threadIdx.x;
    const int w = t >> 6, l = t & 63, g = l >> 4, c = l & 15;
    const int wr = w >> 1, wc = w & 1;

    const int arow = t >> 1;
    const int acol0 = (t & 1) * 16;

    const size_t xrow = (size_t)(tm * 128 + arow) * K;
    const size_t wrow = (size_t)(tn * 128 + arow) * K;

    f32x4 acc[4][4] = {};

    for (int k0 = 0; k0 < K; k0 += 32) {
        __syncthreads();
        *reinterpret_cast<bf16x8*>(&As[arow][acol0])     = ldb8(&X[xrow + k0 + acol0]);
        *reinterpret_cast<bf16x8*>(&As[arow][acol0 + 8]) = ldb8(&X[xrow + k0 + acol0 + 8]);
        *reinterpret_cast<bf16x8*>(&Bs[arow][acol0])     = ldb8(&Wt[wrow + k0 + acol0]);
        *reinterpret_cast<bf16x8*>(&Bs[arow][acol0 + 8]) = ldb8(&Wt[wrow + k0 + acol0 + 8]);
        __syncthreads();

        bf16x8 am[4], bn[4];
#pragma unroll
        for (int mi = 0; mi < 4; ++mi) am[mi] = ldb8(&As[wr * 64 + mi * 16 + c][g * 8]);
#pragma unroll
        for (int ni = 0; ni < 4; ++ni) bn[ni] = ldb8(&Bs[wc * 64 + ni * 16 + c][g * 8]);
#pragma unroll
        for (int mi = 0; mi < 4; ++mi)
#pragma unroll
            for (int ni = 0; ni < 4; ++ni)
                acc[mi][ni] = mfma16(am[mi], bn[ni], acc[mi][ni]);
    }

#pragma unroll
    for (int mi = 0; mi < 4; ++mi) {
        const int mbase = tm * 128 + wr * 64 + mi * 16 + g * 4;
#pragma unroll
        for (int ni = 0; ni < 4; ++ni) {
            const int n = tn * 128 + wc * 64 + ni * 16 + c;
#pragma unroll
            for (int r = 0; r < 4; ++r) {
                const int mm = mbase + r;
                float v = acc[mi][ni][r];
                if (MODE == 0) {
                    const float* bp = (n < 1024) ? bias0 : (n < 2048) ? bias1 : bias2;
                    const int nn = n & 1023;
                    v += bp[nn];
                    const int b = mm >> 11, s = mm & 2047;
                    const int h = nn >> 6, hd = nn & 63;
                    const size_t bh = (size_t)(b * H_ + h);
                    const __hip_bfloat16 bvv = __float2bfloat16(v);
                    if (n < 2048) {
                        __hip_bfloat16* dst = (n < 1024) ? Yq : Yk;
                        dst[(bh * S_ + s) * HD_ + hd] = bvv;
                    } else {
                        Yv[(bh * HD_ + hd) * S_ + s] = bvv;
                    }
                } else {
                    Yo[(size_t)mm * N + n] = v + bias0[n];
                }
            }
        }
    }
}

// ---------------- fused attention: QBLK=32 via dual q-groups per wave ----------------
// grid: B*H*(S/32) blocks of 8 waves. Block owns 32 q-rows (two 16-row groups
// A,B); wave w owns k in [w*256, (w+1)*256). Swapped mfma(K,Q) per group with
// SHARED K/mask/V loads. P~ = exp(s+m) packed bf16, 32 VGPRs per group.
// NO launch-bounds VGPR clamp (r6's (512,4) forced spills); regular cached
// stores (NT removed); per-W order: shuffles -> V loads -> MFMA -> stores.
__global__ __launch_bounds__(512) void attn_kernel(
    const __hip_bfloat16* __restrict__ Qh, const __hip_bfloat16* __restrict__ Kh,
    const __hip_bfloat16* __restrict__ Vt, const float* __restrict__ mask,
    float* __restrict__ probs, __hip_bfloat16* __restrict__ ctx) {
    __shared__ float Cred[8][16][68];   // 34816 B, reused for group A then B
    __shared__ float sred[8][32];
    __shared__ float invsh[32];

    const int blk = blockIdx.x;
    const int qt = blk & 63;         // S/32
    const int bh = blk >> 6;
    const int b = bh >> 4, h = bh & 15;
    const int t = threadIdx.x;
    const int w = t >> 6, l = t & 63, g = l >> 4, c = l & 15;
    const int q0 = qt * 32;
    const int kbase = w * 256;

    const __hip_bfloat16* Qb = Qh + (size_t)bh * S_ * HD_;
    const __hip_bfloat16* Kb = Kh + (size_t)bh * S_ * HD_;
    const __hip_bfloat16* Vb = Vt + (size_t)bh * HD_ * S_;
    const float* mrow = mask + (size_t)b * S_;

    const bf16x8 aqA0 = ldb8(&Qb[(q0 + c) * HD_ + g * 8]);
    const bf16x8 aqA1 = ldb8(&Qb[(q0 + c) * HD_ + 32 + g * 8]);
    const bf16x8 aqB0 = ldb8(&Qb[(q0 + 16 + c) * HD_ + g * 8]);
    const bf16x8 aqB1 = ldb8(&Qb[(q0 + 16 + c) * HD_ + 32 + g * 8]);

    // ---- pass 1: QK^T + exp once; P~ packed bf16 (per group) ----
    unsigned int uA[16][2], uB[16][2];
    float lsumA = 0.f, lsumB = 0.f;
#pragma unroll
    for (int s = 0; s < 16; ++s) {
        const int kk = kbase + s * 16;
        const bf16x8 k0 = ldb8(&Kb[(kk + c) * HD_ + g * 8]);
        const bf16x8 k1 = ldb8(&Kb[(kk + c) * HD_ + 32 + g * 8]);
        f32x4 aA = {}, aB = {};
        aA = mfma16(k0, aqA0, aA);
        aA = mfma16(k1, aqA1, aA);
        aB = mfma16(k0, aqB0, aB);
        aB = mfma16(k1, aqB1, aB);
        const float4 mk = *reinterpret_cast<const float4*>(&mrow[kk + g * 4]);
        const float pA0 = __expf(aA[0] * 0.125f + mk.x);
        const float pA1 = __expf(aA[1] * 0.125f + mk.y);
        const float pA2 = __expf(aA[2] * 0.125f + mk.z);
        const float pA3 = __expf(aA[3] * 0.125f + mk.w);
        const float pB0 = __expf(aB[0] * 0.125f + mk.x);
        const float pB1 = __expf(aB[1] * 0.125f + mk.y);
        const float pB2 = __expf(aB[2] * 0.125f + mk.z);
        const float pB3 = __expf(aB[3] * 0.125f + mk.w);
        lsumA += (pA0 + pA1) + (pA2 + pA3);
        lsumB += (pB0 + pB1) + (pB2 + pB3);
        union { __hip_bfloat16 hh[2]; unsigned int ui; } w0, w1;
        w0.hh[0] = __float2bfloat16(pA0); w0.hh[1] = __float2bfloat16(pA1);
        w1.hh[0] = __float2bfloat16(pA2); w1.hh[1] = __float2bfloat16(pA3);
        uA[s][0] = w0.ui; uA[s][1] = w1.ui;
        w0.hh[0] = __float2bfloat16(pB0); w0.hh[1] = __float2bfloat16(pB1);
        w1.hh[0] = __float2bfloat16(pB2); w1.hh[1] = __float2bfloat16(pB3);
        uB[s][0] = w0.ui; uB[s][1] = w1.ui;
    }
    lsumA += __shfl_xor(lsumA, 16); lsumA += __shfl_xor(lsumA, 32);
    lsumB += __shfl_xor(lsumB, 16); lsumB += __shfl_xor(lsumB, 32);
    if (g == 0) { sred[w][c] = lsumA; sred[w][16 + c] = lsumB; }
    __syncthreads();
    float totA = 0.f, totB = 0.f;
#pragma unroll
    for (int w8 = 0; w8 < 8; ++w8) { totA += sred[w8][c]; totB += sred[w8][16 + c]; }
    const float invA = 1.0f / totA;
    const float invB = 1.0f / totB;
    if (w == 0 && g == 0) { invsh[c] = invA; invsh[16 + c] = invB; }

    // ---- pass 2: PV (shuffle A-frags) then probs stores, per 32-k window ----
    f32x4 caccA[4] = {}, caccB[4] = {};
    float* prowA = probs + ((size_t)bh * S_ + q0 + c) * S_ + kbase;
    float* prowB = probs + ((size_t)bh * S_ + q0 + 16 + c) * S_ + kbase;
    const int src0 = 32 * (g & 1) + c;
    const int src1 = src0 + 16;
    const int sigma = g >> 1;
#pragma unroll
    for (int W = 0; W < 8; ++W) {
        // A-frags: af.ui[jj] = u[2W+sigma][jj&1] from lane 32(g&1)+16(jj>>1)+c
        union { unsigned int ui[4]; bf16x8 v; } afA, afB;
        {
            const unsigned int x00 = __shfl(uA[2 * W][0], src0);
            const unsigned int x10 = __shfl(uA[2 * W + 1][0], src0);
            const unsigned int x01 = __shfl(uA[2 * W][1], src0);
            const unsigned int x11 = __shfl(uA[2 * W + 1][1], src0);
            const unsigned int x02 = __shfl(uA[2 * W][0], src1);
            const unsigned int x12 = __shfl(uA[2 * W + 1][0], src1);
            const unsigned int x03 = __shfl(uA[2 * W][1], src1);
            const unsigned int x13 = __shfl(uA[2 * W + 1][1], src1);
            afA.ui[0] = sigma ? x10 : x00;
            afA.ui[1] = sigma ? x11 : x01;
            afA.ui[2] = sigma ? x12 : x02;
            afA.ui[3] = sigma ? x13 : x03;
        }
        {
            const unsigned int x00 = __shfl(uB[2 * W][0], src0);
            const unsigned int x10 = __shfl(uB[2 * W + 1][0], src0);
            const unsigned int x01 = __shfl(uB[2 * W][1], src0);
            const unsigned int x11 = __shfl(uB[2 * W + 1][1], src0);
            const unsigned int x02 = __shfl(uB[2 * W][0], src1);
            const unsigned int x12 = __shfl(uB[2 * W + 1][0], src1);
            const unsigned int x03 = __shfl(uB[2 * W][1], src1);
            const unsigned int x13 = __shfl(uB[2 * W + 1][1], src1);
            afB.ui[0] = sigma ? x10 : x00;
            afB.ui[1] = sigma ? x11 : x01;
            afB.ui[2] = sigma ? x12 : x02;
            afB.ui[3] = sigma ? x13 : x03;
        }
        const int kk = kbase + 32 * W;
#pragma unroll
        for (int n = 0; n < 4; ++n) {
            const bf16x8 bv = ldb8(&Vb[(n * 16 + c) * S_ + kk + g * 8]);  // shared
            caccA[n] = mfma16(afA.v, bv, caccA[n]);
            caccB[n] = mfma16(afB.v, bv, caccB[n]);
        }
        // probs stores (regular cached), off the MFMA-dependent path
#pragma unroll
        for (int ss = 0; ss < 2; ++ss) {
            const int s = 2 * W + ss;
            f32x4 oA, oB;
            oA[0] = __uint_as_float(uA[s][0] << 16) * invA;
            oA[1] = __uint_as_float(uA[s][0] & 0xffff0000u) * invA;
            oA[2] = __uint_as_float(uA[s][1] << 16) * invA;
            oA[3] = __uint_as_float(uA[s][1] & 0xffff0000u) * invA;
            *reinterpret_cast<f32x4*>(&prowA[s * 16 + g * 4]) = oA;
            oB[0] = __uint_as_float(uB[s][0] << 16) * invB;
            oB[1] = __uint_as_float(uB[s][0] & 0xffff0000u) * invB;
            oB[2] = __uint_as_float(uB[s][1] << 16) * invB;
            oB[3] = __uint_as_float(uB[s][1] & 0xffff0000u) * invB;
            *reinterpret_cast<f32x4*>(&prowB[s * 16 + g * 4]) = oB;
        }
    }

    // ---- cross-wave PV reduce: group A, then group B through same LDS ----
#pragma unroll
    for (int n = 0; n < 4; ++n)
#pragma unroll
        for (int r = 0; r < 4; ++r)
            Cred[w][g * 4 + r][n * 16 + c] = caccA[n][r];
    __syncthreads();
    {
        const int row = t >> 5, col2 = (t & 31) * 2;
        float a0 = 0.f, a1 = 0.f;
#pragma unroll
        for (int w8 = 0; w8 < 8; ++w8) {
            const float2 vv = *reinterpret_cast<const float2*>(&Cred[w8][row][col2]);
            a0 += vv.x; a1 += vv.y;
        }
        const float fin = invsh[row];
        union { __hip_bfloat16 hh[2]; unsigned int ui; } ov;
        ov.hh[0] = __float2bfloat16(a0 * fin);
        ov.hh[1] = __float2bfloat16(a1 * fin);
        *reinterpret_cast<unsigned int*>(
            &ctx[((size_t)b * S_ + q0 + row) * D_ + h * HD_ + col2]) = ov.ui;
    }
    __syncthreads();
#pragma unroll
    for (int n = 0; n < 4; ++n)
#pragma unroll
        for (int r = 0; r < 4; ++r)
            Cred[w][g * 4 + r][n * 16 + c] = caccB[n][r];
    __syncthreads();
    {
        const int row = t >> 5, col2 = (t & 31) * 2;
        float a0 = 0.f, a1 = 0.f;
#pragma unroll
        for (int w8 = 0; w8 < 8; ++w8) {
            const float2 vv = *reinterpret_cast<const float2*>(&Cred[w8][row][col2]);
            a0 += vv.x; a1 += vv.y;
        }
        const float fin = invsh[16 + row];
        union { __hip_bfloat16 hh[2]; unsigned int ui; } ov;
        ov.hh[0] = __float2bfloat16(a0 * fin);
        ov.hh[1] = __float2bfloat16(a1 * fin);
        *reinterpret_cast<unsigned int*>(
            &ctx[((size_t)b * S_ + q0 +16 + row) * D_ + h * HD_ + col2]) = ov.ui;
    }
}

// ---------------- launch ----------------
extern "C" void kernel_launch(void* const* d_in, const int* in_sizes, int n_in,
                              void* d_out, int out_size, void* d_ws, size_t ws_size,
                              hipStream_t stream) {
    const float* hs   = (const float*)d_in[0];
    const float* mask = (const float*)d_in[1];
    const float* Wq   = (const float*)d_in[2];
    const float* bq   = (const float*)d_in[3];
    const float* Wk   = (const float*)d_in[4];
    const float* bk   = (const float*)d_in[5];
    const float* Wv   = (const float*)d_in[6];
    const float* bv   = (const float*)d_in[7];
    const float* Wo   = (const float*)d_in[8];
    const float* bo   = (const float*)d_in[9];

    float* out   = (float*)d_out;
    float* probs = out + (size_t)B_ * S_ * D_;

    const size_t MD = (size_t)B_ * S_ * D_;  // 4096*1024
    __hip_bfloat16* hsb   = (__hip_bfloat16*)d_ws;
    __hip_bfloat16* wqkvb = hsb + MD;
    __hip_bfloat16* wob   = wqkvb + 3u * 1024u * 1024u;
    __hip_bfloat16* Qh    = wob + (size_t)1024 * 1024;
    __hip_bfloat16* Kh    = Qh + MD;
    __hip_bfloat16* Vt    = Kh + MD;
    __hip_bfloat16* ctxb  = Vt + MD;

    conv_kernel<<<4096, 256, 0, stream>>>(hs, hsb, (int)(MD / 4));
    conv_kernel<<<1024, 256, 0, stream>>>(Wq, wqkvb, 262144);
    conv_kernel<<<1024, 256, 0, stream>>>(Wk, wqkvb + 1048576, 262144);
    conv_kernel<<<1024, 256, 0, stream>>>(Wv, wqkvb + 2097152, 262144);
    conv_kernel<<<1024, 256, 0, stream>>>(Wo, wob, 262144);

    gemm_bt<0><<<32 * 24, 256, 0, stream>>>(hsb, wqkvb, bq, bk, bv,
                                            Qh, Kh, Vt, nullptr, 4096, 3072, 1024);

    attn_kernel<<<B_ * H_ * (S_ / 32), 512, 0, stream>>>(Qh, Kh, Vt, mask, probs, ctxb);

    gemm_bt<1><<<32 * 8, 256, 0, stream>>>(ctxb, wob, bo, nullptr, nullptr,
                                           nullptr, nullptr, nullptr, out, 4096, 1024, 1024);
}